// Round 8
// baseline (280.167 us; speedup 1.0000x reference)
//
#include <hip/hip_runtime.h>
#include <cstdint>
#include <cstddef>

// Problem constants
#define B_ 4
#define T_ 2048
#define C_ 1024
#define H_ 16
#define D_ 64

typedef _Float16 f16;
typedef f16 f16x4 __attribute__((ext_vector_type(4)));
typedef f16 f16x8 __attribute__((ext_vector_type(8)));
typedef float f32x4 __attribute__((ext_vector_type(4)));

// Async global->LDS 16B copy. LDS dest is wave-uniform base + lane*16.
__device__ __forceinline__ void async_ld16(const void* g, void* l) {
  __builtin_amdgcn_global_load_lds(
      (const __attribute__((address_space(1))) void*)g,
      (__attribute__((address_space(3))) void*)l,
      16, 0, 0);
}

// ---------------- merged prep: x cvt + two weight transposes (one dispatch) ------
__global__ void k_prep(const float* __restrict__ x, f16* __restrict__ xh,
                       const float* __restrict__ Wqkv, f16* __restrict__ WqkvT,
                       const float* __restrict__ Wout, f16* __restrict__ WoutT)
{
  __shared__ float tile[32][33];
  const int bx = blockIdx.x, t = threadIdx.x;
  if (bx < 8192) {
    int i = bx * 256 + t;
    float4 v = ((const float4*)x)[i];
    f16x4 h;
    h.x = (f16)v.x; h.y = (f16)v.y; h.z = (f16)v.z; h.w = (f16)v.w;
    ((f16x4*)xh)[i] = h;
    return;
  }
  const float* in; f16* out; int K, N, nt, kt;
  if (bx < 8192 + 3072) {
    int idx = bx - 8192; in = Wqkv; out = WqkvT; K = 1024; N = 3072;
    nt = idx % 96; kt = idx / 96;
  } else {
    int idx = bx - 11264; in = Wout; out = WoutT; K = 1024; N = 1024;
    nt = idx % 32; kt = idx / 32;
  }
  int tx = t & 31, ty = t >> 5;
  int k0 = kt * 32, n0 = nt * 32;
#pragma unroll
  for (int i = 0; i < 32; i += 8)
    tile[ty + i][tx] = in[(size_t)(k0 + ty + i) * N + n0 + tx];
  __syncthreads();
#pragma unroll
  for (int i = 0; i < 32; i += 8)
    out[(size_t)(n0 + ty + i) * K + k0 + tx] = (f16)tile[tx][ty + i];
}

// ---------------- GEMM 256x128: C[M][N] = A[M][K] @ Bt^T ------------------------
// m97-family LDS/dbuf structure, 256x128 block tile (wave 128x64). f16 (Ch) or
// f32 (Cf) output; fused V-transpose for QKV cols >= 2048.
__global__ __launch_bounds__(256, 3)
void k_gemm256(const f16* __restrict__ A, const f16* __restrict__ Bt,
               const float* __restrict__ bias, f16* __restrict__ Ch,
               float* __restrict__ Cf, f16* __restrict__ VtOut,
               int M, int N, int K)
{
  __shared__ __align__(16) f16 As[2][256 * 32];
  __shared__ __align__(16) f16 Bs[2][128 * 32];
  const int t = threadIdx.x;
  const int wave = t >> 6, lane = t & 63, lr = lane & 15, quad = lane >> 4;
  const int row0 = blockIdx.y * 256, col0 = blockIdx.x * 128;
  const int wm = (wave >> 1) * 128, wn = (wave & 1) * 64;

  f32x4 acc[8][4] = {};

  const int sw = ((t & 3) ^ ((t >> 4) & 3)) * 8;
  const f16* gA = A + (size_t)(row0 + (t >> 2)) * K + sw;
  const f16* gB = Bt + (size_t)(col0 + (t >> 2)) * K + sw;
  const size_t rowskip = (size_t)64 * K;
  const int rc = (quad ^ (lr >> 2)) * 8;

  {
    f16* lA = As[0] + wave * 512;
    f16* lB = Bs[0] + wave * 512;
    async_ld16(gA,                lA);
    async_ld16(gA + rowskip,      lA + 2048);
    async_ld16(gA + 2 * rowskip,  lA + 4096);
    async_ld16(gA + 3 * rowskip,  lA + 6144);
    async_ld16(gB,                lB);
    async_ld16(gB + rowskip,      lB + 2048);
  }

  const int iters = K >> 5;
  for (int it = 0; it < iters; ++it) {
    __syncthreads();
    const int buf = it & 1;
    if (it + 1 < iters) {
      const int k0 = (it + 1) * 32;
      f16* lA = As[buf ^ 1] + wave * 512;
      f16* lB = Bs[buf ^ 1] + wave * 512;
      async_ld16(gA + k0,               lA);
      async_ld16(gA + rowskip + k0,     lA + 2048);
      async_ld16(gA + 2 * rowskip + k0, lA + 4096);
      async_ld16(gA + 3 * rowskip + k0, lA + 6144);
      async_ld16(gB + k0,               lB);
      async_ld16(gB + rowskip + k0,     lB + 2048);
    }
    const f16* As_ = As[buf];
    const f16* Bs_ = Bs[buf];

    f16x8 bf[4];
#pragma unroll
    for (int i = 0; i < 4; ++i)
      bf[i] = *(const f16x8*)&Bs_[(wn + i * 16 + lr) * 32 + rc];
#pragma unroll
    for (int mi = 0; mi < 8; ++mi) {
      f16x8 af = *(const f16x8*)&As_[(wm + mi * 16 + lr) * 32 + rc];
#pragma unroll
      for (int ni = 0; ni < 4; ++ni)
        acc[mi][ni] = __builtin_amdgcn_mfma_f32_16x16x32_f16(af, bf[ni], acc[mi][ni], 0, 0, 0);
    }
  }

  if (VtOut != nullptr && col0 >= 2048) {
#pragma unroll
    for (int ni = 0; ni < 4; ++ni) {
      const int cb = col0 + wn + ni * 16 - 2048;
      const int h = cb >> 6;
      const int dd = (cb & 63) + lr;
      const float bv = bias[2048 + cb + lr];
#pragma unroll
      for (int mi = 0; mi < 8; ++mi) {
#pragma unroll
        for (int r = 0; r < 4; ++r) {
          const int row = row0 + wm + mi * 16 + quad * 4 + r;
          const int bb = row >> 11, tt = row & 2047;
          VtOut[((size_t)(bb * 16 + h) * 64 + dd) * T_ + tt] = (f16)(acc[mi][ni][r] + bv);
        }
      }
    }
  } else if (Ch != nullptr) {
#pragma unroll
    for (int mi = 0; mi < 8; ++mi) {
#pragma unroll
      for (int ni = 0; ni < 4; ++ni) {
        int col = col0 + wn + ni * 16 + lr;
        float bv = bias[col];
#pragma unroll
        for (int r = 0; r < 4; ++r) {
          int row = row0 + wm + mi * 16 + quad * 4 + r;
          Ch[(size_t)row * N + col] = (f16)(acc[mi][ni][r] + bv);
        }
      }
    }
  } else {
#pragma unroll
    for (int mi = 0; mi < 8; ++mi) {
#pragma unroll
      for (int ni = 0; ni < 4; ++ni) {
        int col = col0 + wn + ni * 16 + lr;
        float bv = bias[col];
#pragma unroll
        for (int r = 0; r < 4; ++r) {
          int row = row0 + wm + mi * 16 + quad * 4 + r;
          Cf[(size_t)row * N + col] = acc[mi][ni][r] + bv;
        }
      }
    }
  }
}

// ---------------- flash attention (causal), S-transposed formulation -------------
// Round-8: compute S^T = K . Q^T (A-operand = K from LDS, B-operand = register Q;
// B-frag layout == the A-frag layout already loaded). S^T's C-layout (lane holds
// s = mt*16+quad*4+r, q = lr) IS the B-operand layout of mfma_f32_16x16x16f16
// (k = quad*4+j, n = lr), so after exp+pack P feeds PV directly from registers:
// the P LDS round-trip (16 writes + 2 b128 reads per tile-comp) is gone.
// PV: O^T = V^T . P with A-frags read from the Vt[d][s] LDS tile (b64).
// K-frags and V-frags are shared between paired tiles A and B (one read, two
// MFMAs). l is a single scalar per lane (q = lr), reduced across quads once at
// the end; normalization is one uniform mul. exp uses exp2 with ln2^-1 folded
// into the Q scale. LDS/iter/wave: 8 b128 (K) + 16 b64 (V), ~192 cyc for BOTH
// tiles (was ~309 per single tile-comp) -> LDS floor ~31 us.
__global__ __launch_bounds__(256, 4)
void k_flash(const f16* __restrict__ QKV, const f16* __restrict__ Vt, f16* __restrict__ O)
{
  __shared__ __align__(16) f16 Ks[2][64 * 64];
  __shared__ __align__(16) f16 Vs[2][64 * 64];

  const int a = blockIdx.x, bh = blockIdx.y;
  const int b = bh >> 4, h = bh & 15;
  const int qtA = a, qtB = 31 - a;     // qtA <= 15 < qtB
  const int t = threadIdx.x, wave = t >> 6, lane = t & 63, lr = lane & 15, quad = lane >> 4;
  const int lr3 = lr & 7;
  const int c0 = quad ^ lr3;           // K-frag swizzled chunk for d=quad*8
  const int c1 = c0 ^ 4;               // d=32+quad*8

  // Q fragments (used as MFMA B-operand; layout identical to A-frag):
  // lane holds Q[q=lr][d=quad*8+j]. Scale = 0.125 * log2(e) so exp2 suffices.
  const f16 scl = (f16)0.18033688f;
  const f16* qpA = QKV + (size_t)(b * T_ + qtA * 64 + wave * 16 + lr) * 3072 + h * 64;
  const f16* qpB = QKV + (size_t)(b * T_ + qtB * 64 + wave * 16 + lr) * 3072 + h * 64;
  f16x8 qA0 = *(const f16x8*)(qpA + quad * 8)      * scl;
  f16x8 qA1 = *(const f16x8*)(qpA + 32 + quad * 8) * scl;
  f16x8 qB0 = *(const f16x8*)(qpB + quad * 8)      * scl;
  f16x8 qB1 = *(const f16x8*)(qpB + 32 + quad * 8) * scl;

  float lA = 0.f, lB = 0.f;
  f32x4 oA[4] = {}, oB[4] = {};   // O^T: lane holds d = dt*16+quad*4+r, q = lr

  // staging (chunk-XOR swizzle on global source address)
  const int sw = ((t & 7) ^ ((t >> 3) & 7)) * 8;
  const f16* gK = QKV + (size_t)(b * T_ + (t >> 3)) * 3072 + 1024 + h * 64 + sw;
  const f16* gV = Vt + ((size_t)bh * 64 + (t >> 3)) * T_ + sw;

  // V A-frag addressing: element (d, s) stored at d*64 + ((s>>3)^(d&7))*8 + (s&7).
  // Read d = dt*16+lr, s = kc*16 + quad*4 + j (j=0..3, b64).
  const int vbase = lr * 64 + (quad & 1) * 4;
  int voff[4];
#pragma unroll
  for (int kc = 0; kc < 4; ++kc)
    voff[kc] = (((2 * kc + (quad >> 1)) ^ lr3) << 3);

  const int last = qtB;

  {
    f16* lK = Ks[0] + wave * 512;
    f16* lV = Vs[0] + wave * 512;
    async_ld16(gK,                     lK);
    async_ld16(gK + (size_t)32 * 3072, lK + 2048);
    async_ld16(gV,                     lV);
    async_ld16(gV + (size_t)32 * T_,   lV + 2048);
  }

  for (int kt = 0; kt <= last; ++kt) {
    __syncthreads();
    const int buf = kt & 1;
    if (kt < last) {
      const f16* gk = gK + (size_t)((kt + 1) * 64) * 3072;
      const f16* gv = gV + (kt + 1) * 64;
      f16* lK = Ks[buf ^ 1] + wave * 512;
      f16* lV = Vs[buf ^ 1] + wave * 512;
      async_ld16(gk,                     lK);
      async_ld16(gk + (size_t)32 * 3072, lK + 2048);
      async_ld16(gv,                     lV);
      async_ld16(gv + (size_t)32 * T_,   lV + 2048);
    }
    const f16* K_ = Ks[buf];
    const f16* V_ = Vs[buf];
    const bool actA = (kt <= qtA);

    // S^T = K . Q^T for both tiles, sharing K fragments
    f32x4 sB[4], sA[4];
#pragma unroll
    for (int mt = 0; mt < 4; ++mt) {
      const f16* kr = K_ + (mt * 16 + lr) * 64;
      f16x8 k0 = *(const f16x8*)(kr + c0 * 8);
      f16x8 k1 = *(const f16x8*)(kr + c1 * 8);
      f32x4 z = {};
      z = __builtin_amdgcn_mfma_f32_16x16x32_f16(k0, qB0, z, 0, 0, 0);
      z = __builtin_amdgcn_mfma_f32_16x16x32_f16(k1, qB1, z, 0, 0, 0);
      sB[mt] = z;
      if (actA) {
        f32x4 y = {};
        y = __builtin_amdgcn_mfma_f32_16x16x32_f16(k0, qA0, y, 0, 0, 0);
        y = __builtin_amdgcn_mfma_f32_16x16x32_f16(k1, qA1, y, 0, 0, 0);
        sA[mt] = y;
      }
    }

    // diagonal masks: s_local = mt*16+quad*4+r vs q_local = wave*16+lr
    const int qloc = wave * 16 + lr;
    if (kt == qtB) {
#pragma unroll
      for (int mt = 0; mt < 4; ++mt)
#pragma unroll
        for (int r = 0; r < 4; ++r)
          if (mt * 16 + quad * 4 + r > qloc) sB[mt][r] = -1e30f;
    }
    if (kt == qtA) {
#pragma unroll
      for (int mt = 0; mt < 4; ++mt)
#pragma unroll
        for (int r = 0; r < 4; ++r)
          if (mt * 16 + quad * 4 + r > qloc) sA[mt][r] = -1e30f;
    }

    // exp2 + pack to P fragments (registers; B-operand of 16x16x16 MFMA)
    f16x4 pB[4], pA[4];
#pragma unroll
    for (int mt = 0; mt < 4; ++mt) {
#pragma unroll
      for (int r = 0; r < 4; ++r) {
        float e = exp2f(sB[mt][r]);
        lB += e;
        pB[mt][r] = (f16)e;
      }
    }
    if (actA) {
#pragma unroll
      for (int mt = 0; mt < 4; ++mt) {
#pragma unroll
        for (int r = 0; r < 4; ++r) {
          float e = exp2f(sA[mt][r]);
          lA += e;
          pA[mt][r] = (f16)e;
        }
      }
    }

    // O^T += V^T . P, sharing V fragments between tiles
#pragma unroll
    for (int dt = 0; dt < 4; ++dt) {
      const f16* vb = V_ + dt * 1024 + vbase;
#pragma unroll
      for (int kc = 0; kc < 4; ++kc) {
        f16x4 va = *(const f16x4*)(vb + voff[kc]);
        oB[dt] = __builtin_amdgcn_mfma_f32_16x16x16f16(va, pB[kc], oB[dt], 0, 0, 0);
        if (actA)
          oA[dt] = __builtin_amdgcn_mfma_f32_16x16x16f16(va, pA[kc], oA[dt], 0, 0, 0);
      }
    }
  }

  // epilogue: reduce l across quads (lanes lr, lr+16, lr+32, lr+48), normalize
  lA += __shfl_xor(lA, 16, 64);
  lA += __shfl_xor(lA, 32, 64);
  lB += __shfl_xor(lB, 16, 64);
  lB += __shfl_xor(lB, 32, 64);
  const float invA = 1.f / lA;
  const float invB = 1.f / lB;
  const int rowA = qtA * 64 + wave * 16 + lr;
  const int rowB = qtB * 64 + wave * 16 + lr;
  f16* oAp = O + (size_t)(b * T_ + rowA) * C_ + h * 64 + quad * 4;
  f16* oBp = O + (size_t)(b * T_ + rowB) * C_ + h * 64 + quad * 4;
#pragma unroll
  for (int dt = 0; dt < 4; ++dt) {
    f16x4 ha, hb;
#pragma unroll
    for (int r = 0; r < 4; ++r) {
      ha[r] = (f16)(oA[dt][r] * invA);
      hb[r] = (f16)(oB[dt][r] * invB);
    }
    *(f16x4*)(oAp + dt * 16) = ha;
    *(f16x4*)(oBp + dt * 16) = hb;
  }
}

// ---------------- launch ----------------
extern "C" void kernel_launch(void* const* d_in, const int* in_sizes, int n_in,
                              void* d_out, int out_size, void* d_ws, size_t ws_size,
                              hipStream_t stream)
{
  const float* x    = (const float*)d_in[0];
  const float* Wqkv = (const float*)d_in[1];
  const float* bqkv = (const float*)d_in[2];
  const float* Wout = (const float*)d_in[3];
  const float* bout = (const float*)d_in[4];
  float* out = (float*)d_out;

  f16* xh    = (f16*)d_ws;                            // 8192*1024
  f16* WqkvT = xh + (size_t)8192 * 1024;              // 3072*1024
  f16* WoutT = WqkvT + (size_t)3072 * 1024;           // 1024*1024
  f16* QKV   = WoutT + (size_t)1024 * 1024;           // 8192*3072 (V region unused)
  f16* VtG   = QKV + (size_t)8192 * 3072;             // 64*64*2048
  f16* Oh    = VtG + (size_t)64 * 64 * 2048;          // 8192*1024

  k_prep<<<12288, 256, 0, stream>>>(x, xh, Wqkv, WqkvT, Wout, WoutT);

  // QKV projection; V columns go directly (transposed) to VtG
  k_gemm256<<<dim3(3072 / 128, 8192 / 256), 256, 0, stream>>>(
      xh, WqkvT, bqkv, QKV, nullptr, VtG, 8192, 3072, 1024);

  k_flash<<<dim3(16, B_ * H_), 256, 0, stream>>>(QKV, VtG, Oh);

  // output projection -> f32 out
  k_gemm256<<<dim3(1024 / 128, 8192 / 256), 256, 0, stream>>>(
      Oh, WoutT, bout, nullptr, out, nullptr, 8192, 1024, 1024);
}